// Round 6
// baseline (1132.893 us; speedup 1.0000x reference)
//
#include <hip/hip_runtime.h>
#include <hip/hip_bf16.h>

// Model dims
#define VOCAB 21128
#define EMBED 768
#define DMODEL 256
#define HID 100
#define NTAGS 21
#define BB 32
#define TT 256
#define NTOK (BB*TT)   // 8192 tokens, token index i = t*BB + b

typedef float f32x4 __attribute__((ext_vector_type(4)));

__device__ __forceinline__ float sigm(float x) { return 1.0f / (1.0f + __expf(-x)); }
__device__ __forceinline__ float tanh_(float x) { return 2.0f / (1.0f + __expf(-2.0f * x)) - 1.0f; }

// ---------------------------------------------------------------------------
// Generic SGEMM: C(M x N) = A(M x K) @ B(N x K)^T + bias1 + bias2
// ---------------------------------------------------------------------------
__global__ __launch_bounds__(256) void gemm_bias(
    const float* __restrict__ A, int lda,
    const float* __restrict__ B, int ldb,
    const float* __restrict__ bias1, const float* __restrict__ bias2,
    float* __restrict__ C, int ldc,
    int M, int N, int K,
    const int* __restrict__ gatherWords)
{
    __shared__ float As[8][64];
    __shared__ float Bs[8][64];
    const int row0 = blockIdx.x * 64;
    const int col0 = blockIdx.y * 64;
    const int tid = threadIdx.x;
    const int tx = tid & 15;        // 0..15 -> cols
    const int ty = tid >> 4;        // 0..15 -> rows
    float acc[4][4] = {};

    for (int k0 = 0; k0 < K; k0 += 8) {
        if (tid < 128) {
            int r = tid >> 1, q = tid & 1;
            int grow = row0 + r;
            const float* ap;
            if (gatherWords) {
                int widx = gatherWords[(grow & 31) * TT + (grow >> 5)];
                ap = A + (size_t)widx * lda;
            } else {
                ap = A + (size_t)grow * lda;
            }
            float4 v = *(const float4*)(ap + k0 + q * 4);
            As[q*4+0][r] = v.x; As[q*4+1][r] = v.y;
            As[q*4+2][r] = v.z; As[q*4+3][r] = v.w;
        } else {
            int f = tid - 128;
            int r = f >> 1, q = f & 1;
            int gcol = col0 + r;
            float4 v = make_float4(0.f, 0.f, 0.f, 0.f);
            if (gcol < N) v = *(const float4*)(B + (size_t)gcol * ldb + k0 + q * 4);
            Bs[q*4+0][r] = v.x; Bs[q*4+1][r] = v.y;
            Bs[q*4+2][r] = v.z; Bs[q*4+3][r] = v.w;
        }
        __syncthreads();
        #pragma unroll
        for (int kk = 0; kk < 8; ++kk) {
            float4 av = *(const float4*)&As[kk][ty * 4];
            float4 bv = *(const float4*)&Bs[kk][tx * 4];
            acc[0][0] += av.x * bv.x; acc[0][1] += av.x * bv.y;
            acc[0][2] += av.x * bv.z; acc[0][3] += av.x * bv.w;
            acc[1][0] += av.y * bv.x; acc[1][1] += av.y * bv.y;
            acc[1][2] += av.y * bv.z; acc[1][3] += av.y * bv.w;
            acc[2][0] += av.z * bv.x; acc[2][1] += av.z * bv.y;
            acc[2][2] += av.z * bv.z; acc[2][3] += av.z * bv.w;
            acc[3][0] += av.w * bv.x; acc[3][1] += av.w * bv.y;
            acc[3][2] += av.w * bv.z; acc[3][3] += av.w * bv.w;
        }
        __syncthreads();
    }

    float bb_[4];
    #pragma unroll
    for (int jj = 0; jj < 4; ++jj) {
        int gcol = col0 + tx * 4 + jj;
        float bv = 0.f;
        if (gcol < N) {
            bv = bias1[gcol];
            if (bias2) bv += bias2[gcol];
        }
        bb_[jj] = bv;
    }
    #pragma unroll
    for (int ii = 0; ii < 4; ++ii) {
        int grow = row0 + ty * 4 + ii;
        #pragma unroll
        for (int jj = 0; jj < 4; ++jj) {
            int gcol = col0 + tx * 4 + jj;
            if (gcol < N) C[(size_t)grow * ldc + gcol] = acc[ii][jj] + bb_[jj];
        }
    }
}

// ---------------------------------------------------------------------------
// LSTM recurrence. 64 blocks = (dir<<5)|b, 448 threads = 7 waves.
// Thread (q,jj): gate q of hidden unit jj.  Two R5 lessons applied:
// (1) h-broadcast was the wall: 25 ds_read_b128 broadcasts/thread/step =
//     ~2100 cyc/step on the shared LDS pipe.  Now ONE cooperative
//     ds_read_b128 (lane l holds h[4l..4l+3]) + v_readlane -> SGPR per
//     k-group; FMA consumes h from the SGPR operand slot.
// (2) weights provably never stayed in VGPRs (VGPR_Count=68 across 3
//     structurally different attempts).  Now stashed in PHYSICAL AGPRs
//     a0..a99 via explicit v_accvgpr_write/read inline asm -- on-chip by
//     construction, no allocator heuristics.  a0-a99 clobbered at every
//     asm site so the allocator never parks compiler values there.
// ---------------------------------------------------------------------------
#define ACLOBS \
  "a0","a1","a2","a3","a4","a5","a6","a7","a8","a9", \
  "a10","a11","a12","a13","a14","a15","a16","a17","a18","a19", \
  "a20","a21","a22","a23","a24","a25","a26","a27","a28","a29", \
  "a30","a31","a32","a33","a34","a35","a36","a37","a38","a39", \
  "a40","a41","a42","a43","a44","a45","a46","a47","a48","a49", \
  "a50","a51","a52","a53","a54","a55","a56","a57","a58","a59", \
  "a60","a61","a62","a63","a64","a65","a66","a67","a68","a69", \
  "a70","a71","a72","a73","a74","a75","a76","a77","a78","a79", \
  "a80","a81","a82","a83","a84","a85","a86","a87","a88","a89", \
  "a90","a91","a92","a93","a94","a95","a96","a97","a98","a99"

#define FOR25(M) \
  M(0,0,1,2,3)      M(1,4,5,6,7)      M(2,8,9,10,11)    M(3,12,13,14,15)  M(4,16,17,18,19) \
  M(5,20,21,22,23)  M(6,24,25,26,27)  M(7,28,29,30,31)  M(8,32,33,34,35)  M(9,36,37,38,39) \
  M(10,40,41,42,43) M(11,44,45,46,47) M(12,48,49,50,51) M(13,52,53,54,55) M(14,56,57,58,59) \
  M(15,60,61,62,63) M(16,64,65,66,67) M(17,68,69,70,71) M(18,72,73,74,75) M(19,76,77,78,79) \
  M(20,80,81,82,83) M(21,84,85,86,87) M(22,88,89,90,91) M(23,92,93,94,95) M(24,96,97,98,99)

__global__ __launch_bounds__(448, 1) void lstm_layer(
    const float* __restrict__ pre,
    const float* __restrict__ Whh,
    float* __restrict__ hout)
{
    const int dir = blockIdx.x >> 5;
    const int b = blockIdx.x & 31;
    const int tid = threadIdx.x;
    const int wave = tid >> 6;              // 0..6
    const int lane = tid & 63;
    const int q = lane >> 4;                // gate 0..3 (i,f,g,o)
    const int jj = (wave << 4) | (lane & 15);  // hidden unit 0..111
    const bool act = (jj < HID);
    const int jc = act ? jj : (HID - 1);    // clamped row (in-bounds load)

    __shared__ alignas(16) float h_lds[2][112];

    // ---- stash weight row Whh[dir][q*HID+jc][:] into AGPRs a0..a99 ----
    const f32x4* wr = (const f32x4*)(Whh + ((size_t)dir * 400 + q * HID + jc) * HID);
#define STASH(K,A0,A1,A2,A3) { f32x4 w = wr[K]; \
    asm volatile("v_accvgpr_write_b32 a" #A0 ", %0\n\t" \
                 "v_accvgpr_write_b32 a" #A1 ", %1\n\t" \
                 "v_accvgpr_write_b32 a" #A2 ", %2\n\t" \
                 "v_accvgpr_write_b32 a" #A3 ", %3" \
                 :: "v"(w.x), "v"(w.y), "v"(w.z), "v"(w.w) : ACLOBS); }
    FOR25(STASH)
#undef STASH

    float c = 0.f;
    if (tid < 112) { h_lds[0][tid] = 0.f; h_lds[1][tid] = 0.f; }
    __syncthreads();

    const int rowoff = dir * 400 + q * HID + jj;
    const int t0 = dir ? (TT - 1) : 0;
    float pcur = act ? pre[(size_t)(t0 * BB + b) * 800 + rowoff] : 0.f;
    const int cl = (lane < 25) ? lane : 24;   // cooperative h-read slot

    for (int s = 0; s < TT; ++s) {
        const int t = dir ? (TT - 1 - s) : s;
        const int i = t * BB + b;

        // prefetch next step's pre (consumed after the next barrier)
        float pnxt = 0.f;
        if (s + 1 < TT) {
            const int tn = dir ? (TT - 2 - s) : (s + 1);
            if (act) pnxt = pre[(size_t)(tn * BB + b) * 800 + rowoff];
        }

        // ONE cooperative LDS read: lane l (0..24) holds h[4l..4l+3]
        const f32x4* hb4 = (const f32x4*)h_lds[s & 1];
        f32x4 hv = hb4[cl];
        const int hx = __float_as_int(hv.x);
        const int hy = __float_as_int(hv.y);
        const int hz = __float_as_int(hv.z);
        const int hw = __float_as_int(hv.w);

        // matvec: acc += W_row . h ; W from AGPRs, h via readlane (SGPR)
        float acc0 = 0.f, acc1 = 0.f, acc2 = 0.f, acc3 = 0.f;
#define GRP(K,A0,A1,A2,A3) { \
        const int s0 = __builtin_amdgcn_readlane(hx, K); \
        const int s1 = __builtin_amdgcn_readlane(hy, K); \
        const int s2 = __builtin_amdgcn_readlane(hz, K); \
        const int s3 = __builtin_amdgcn_readlane(hw, K); \
        float t0_, t1_, t2_, t3_; \
        asm volatile("v_accvgpr_read_b32 %4, a" #A0 "\n\t" \
                     "v_accvgpr_read_b32 %5, a" #A1 "\n\t" \
                     "v_accvgpr_read_b32 %6, a" #A2 "\n\t" \
                     "v_accvgpr_read_b32 %7, a" #A3 "\n\t" \
                     "v_fmac_f32 %0, %4, %8\n\t" \
                     "v_fmac_f32 %1, %5, %9\n\t" \
                     "v_fmac_f32 %2, %6, %10\n\t" \
                     "v_fmac_f32 %3, %7, %11" \
                     : "+v"(acc0), "+v"(acc1), "+v"(acc2), "+v"(acc3), \
                       "=&v"(t0_), "=&v"(t1_), "=&v"(t2_), "=&v"(t3_) \
                     : "s"(s0), "s"(s1), "s"(s2), "s"(s3) : ACLOBS); }
        FOR25(GRP)
#undef GRP
        float g = pcur + ((acc0 + acc1) + (acc2 + acc3));

        // collect the 4 gates for this hidden unit into the q==0 lane
        const int base = lane & 15;
        float gi = __shfl(g, base +  0, 64);
        float gf = __shfl(g, base + 16, 64);
        float gg = __shfl(g, base + 32, 64);
        float go = __shfl(g, base + 48, 64);

        if (q == 0 && act) {
            float igt = sigm(gi);
            float fgt = sigm(gf);
            float ggt = tanh_(gg);
            float ogt = sigm(go);
            c = fgt * c + igt * ggt;
            float h = ogt * tanh_(c);
            h_lds[(s + 1) & 1][jj] = h;           // write NEXT buffer (no WAR hazard)
            hout[(size_t)i * 200 + dir * HID + jj] = h;
        }
        __syncthreads();
        pcur = pnxt;
    }
}

// ---------------------------------------------------------------------------
// logits + log_softmax: one 32-lane half-wave per token.
// ---------------------------------------------------------------------------
__global__ __launch_bounds__(256) void logits_lsm(
    const float* __restrict__ h1,
    const float* __restrict__ out_w,
    const float* __restrict__ out_b,
    float* __restrict__ logits)
{
    const int lane = threadIdx.x & 63;
    const int wid = (blockIdx.x * 256 + threadIdx.x) >> 6;
    const int half = lane >> 5;
    const int n = lane & 31;
    const int i = wid * 2 + half;
    if (i >= NTOK) return;

    float acc = -1e30f;
    if (n < NTAGS) {
        acc = out_b[n];
        const float4* hr = (const float4*)(h1 + (size_t)i * 200);
        const float4* wr = (const float4*)(out_w + (size_t)n * 200);
        #pragma unroll
        for (int e = 0; e < 50; ++e) {
            float4 h4 = hr[e], w4 = wr[e];
            acc += h4.x * w4.x + h4.y * w4.y + h4.z * w4.z + h4.w * w4.w;
        }
    }
    float m = acc;
    for (int off = 16; off > 0; off >>= 1) m = fmaxf(m, __shfl_xor(m, off, 32));
    float ex = (n < NTAGS) ? __expf(acc - m) : 0.f;
    float s = ex;
    for (int off = 16; off > 0; off >>= 1) s += __shfl_xor(s, off, 32);
    if (n < NTAGS) logits[(size_t)i * NTAGS + n] = acc - m - __logf(s);
}

// ---------------------------------------------------------------------------
// CRF loss: one wave per batch element.
// ---------------------------------------------------------------------------
__global__ __launch_bounds__(64) void crf_kernel(
    const float* __restrict__ logits,
    const int* __restrict__ words,
    const int* __restrict__ target,
    const float* __restrict__ trans,
    const float* __restrict__ start_s,
    const float* __restrict__ end_s,
    float* __restrict__ out)
{
    const int b = blockIdx.x;
    const int j = threadIdx.x;

    float tcol[NTAGS];
    #pragma unroll
    for (int i = 0; i < NTAGS; ++i) tcol[i] = (j < NTAGS) ? trans[i * NTAGS + j] : 0.f;

    float alpha = (j < NTAGS) ? (logits[(size_t)(0 * BB + b) * NTAGS + j] + start_s[j]) : -1e30f;

    for (int t = 1; t < TT; ++t) {
        bool mt = (words[b * TT + t] != 0);
        if (mt) {
            float v[NTAGS];
            float mx = -1e30f;
            #pragma unroll
            for (int i2 = 0; i2 < NTAGS; ++i2) {
                float ai = __shfl(alpha, i2, 64);
                v[i2] = ai + tcol[i2];
                mx = fmaxf(mx, v[i2]);
            }
            float s = 0.f;
            #pragma unroll
            for (int i2 = 0; i2 < NTAGS; ++i2) s += __expf(v[i2] - mx);
            float na = mx + __logf(s) + logits[(size_t)(t * BB + b) * NTAGS + j];
            alpha = (j < NTAGS) ? na : -1e30f;
        }
    }

    float val = (j < NTAGS) ? (alpha + end_s[j]) : -1e30f;
    float mx = val;
    for (int off = 32; off > 0; off >>= 1) mx = fmaxf(mx, __shfl_xor(mx, off, 64));
    float s = (j < NTAGS) ? __expf(val - mx) : 0.f;
    for (int off = 32; off > 0; off >>= 1) s += __shfl_xor(s, off, 64);
    float norm = mx + __logf(s);

    float gold = 0.f, slen = 0.f;
    for (int t = j; t < TT; t += 64) {
        int tg = target[b * TT + t];
        bool m = (words[b * TT + t] != 0);
        if (m) {
            gold += logits[(size_t)(t * BB + b) * NTAGS + tg];
            slen += 1.f;
            if (t >= 1) gold += trans[target[b * TT + t - 1] * NTAGS + tg];
        }
    }
    for (int off = 32; off > 0; off >>= 1) {
        gold += __shfl_xor(gold, off, 64);
        slen += __shfl_xor(slen, off, 64);
    }
    if (j == 0) {
        int len = (int)slen;
        int last = (len > 0) ? (len - 1) : 0;
        int last_tag = target[b * TT + last];
        gold += start_s[target[b * TT + 0]] + end_s[last_tag];
        out[b] = norm - gold;
    }
}

// ---------------------------------------------------------------------------
extern "C" void kernel_launch(void* const* d_in, const int* in_sizes, int n_in,
                              void* d_out, int out_size, void* d_ws, size_t ws_size,
                              hipStream_t stream) {
    const int*   words   = (const int*)  d_in[0];
    const int*   target  = (const int*)  d_in[1];
    const float* embed   = (const float*)d_in[2];
    const float* in_fc_w = (const float*)d_in[3];
    const float* in_fc_b = (const float*)d_in[4];
    const float* Wih0    = (const float*)d_in[5];
    const float* Whh0    = (const float*)d_in[6];
    const float* bih0    = (const float*)d_in[7];
    const float* bhh0    = (const float*)d_in[8];
    const float* Wih1    = (const float*)d_in[9];
    const float* Whh1    = (const float*)d_in[10];
    const float* bih1    = (const float*)d_in[11];
    const float* bhh1    = (const float*)d_in[12];
    const float* out_w   = (const float*)d_in[13];
    const float* out_b   = (const float*)d_in[14];
    const float* trans   = (const float*)d_in[15];
    const float* start_s = (const float*)d_in[16];
    const float* end_s   = (const float*)d_in[17];
    float* out = (float*)d_out;

    float* ws = (float*)d_ws;
    float* x      = ws;
    float* pre    = ws + 2097152;
    float* h0     = ws + 8650752;
    float* h1     = ws;
    float* logits = ws + 1638400;

    gemm_bias<<<dim3(NTOK / 64, DMODEL / 64), 256, 0, stream>>>(
        embed, EMBED, in_fc_w, EMBED, in_fc_b, nullptr,
        x, DMODEL, NTOK, DMODEL, EMBED, words);

    gemm_bias<<<dim3(NTOK / 64, 13), 256, 0, stream>>>(
        x, DMODEL, Wih0, DMODEL, bih0, bhh0,
        pre, 800, NTOK, 800, DMODEL, nullptr);

    lstm_layer<<<64, 448, 0, stream>>>(pre, Whh0, h0);

    gemm_bias<<<dim3(NTOK / 64, 13), 256, 0, stream>>>(
        h0, 200, Wih1, 200, bih1, bhh1,
        pre, 800, NTOK, 800, 200, nullptr);

    lstm_layer<<<64, 448, 0, stream>>>(pre, Whh1, h1);

    logits_lsm<<<NTOK / 8, 256, 0, stream>>>(h1, out_w, out_b, logits);

    crf_kernel<<<BB, 64, 0, stream>>>(logits, words, target, trans, start_s, end_s, out);
}

// Round 7
// 686.895 us; speedup vs baseline: 1.6493x; 1.6493x over previous
//
#include <hip/hip_runtime.h>
#include <hip/hip_bf16.h>

// Model dims
#define VOCAB 21128
#define EMBED 768
#define DMODEL 256
#define HID 100
#define NTAGS 21
#define BB 32
#define TT 256
#define NTOK (BB*TT)   // 8192 tokens, token index i = t*BB + b

typedef float f32x4 __attribute__((ext_vector_type(4)));
typedef unsigned int u32x4 __attribute__((ext_vector_type(4)));

__device__ __forceinline__ float sigm(float x) { return 1.0f / (1.0f + __expf(-x)); }
__device__ __forceinline__ float tanh_(float x) { return 2.0f / (1.0f + __expf(-2.0f * x)) - 1.0f; }

// fp32 -> bf16 with round-to-nearest-even
__device__ __forceinline__ unsigned int bfr(float x) {
    unsigned int u = __float_as_uint(x);
    return (u + 0x7fffu + ((u >> 16) & 1u)) >> 16;
}
__device__ __forceinline__ unsigned int bfpack(float lo, float hi) {
    return (bfr(hi) << 16) | bfr(lo);
}

// ---------------------------------------------------------------------------
// Generic SGEMM: C(M x N) = A(M x K) @ B(N x K)^T + bias1 + bias2
// gatherWords: A rows gathered through embedding.
// permGates: output column gcol (0..799) takes B row / bias from the
//   ORIGINAL gate order: gcol = dir*400 + 4*u + q  ->  src = dir*400 + q*100 + u.
//   (So `pre` is written with unit-major gate packing for the MFMA LSTM.)
// ---------------------------------------------------------------------------
__global__ __launch_bounds__(256) void gemm_bias(
    const float* __restrict__ A, int lda,
    const float* __restrict__ B, int ldb,
    const float* __restrict__ bias1, const float* __restrict__ bias2,
    float* __restrict__ C, int ldc,
    int M, int N, int K,
    const int* __restrict__ gatherWords, int permGates)
{
    __shared__ float As[8][64];
    __shared__ float Bs[8][64];
    const int row0 = blockIdx.x * 64;
    const int col0 = blockIdx.y * 64;
    const int tid = threadIdx.x;
    const int tx = tid & 15;
    const int ty = tid >> 4;
    float acc[4][4] = {};

    for (int k0 = 0; k0 < K; k0 += 8) {
        if (tid < 128) {
            int r = tid >> 1, q = tid & 1;
            int grow = row0 + r;
            const float* ap;
            if (gatherWords) {
                int widx = gatherWords[(grow & 31) * TT + (grow >> 5)];
                ap = A + (size_t)widx * lda;
            } else {
                ap = A + (size_t)grow * lda;
            }
            float4 v = *(const float4*)(ap + k0 + q * 4);
            As[q*4+0][r] = v.x; As[q*4+1][r] = v.y;
            As[q*4+2][r] = v.z; As[q*4+3][r] = v.w;
        } else {
            int f = tid - 128;
            int r = f >> 1, q = f & 1;
            int gcol = col0 + r;
            float4 v = make_float4(0.f, 0.f, 0.f, 0.f);
            if (gcol < N) {
                int src = gcol;
                if (permGates) {
                    int d2 = (gcol >= 400) ? 1 : 0;
                    int rr = gcol - d2 * 400;
                    src = d2 * 400 + (rr & 3) * 100 + (rr >> 2);
                }
                v = *(const float4*)(B + (size_t)src * ldb + k0 + q * 4);
            }
            Bs[q*4+0][r] = v.x; Bs[q*4+1][r] = v.y;
            Bs[q*4+2][r] = v.z; Bs[q*4+3][r] = v.w;
        }
        __syncthreads();
        #pragma unroll
        for (int kk = 0; kk < 8; ++kk) {
            float4 av = *(const float4*)&As[kk][ty * 4];
            float4 bv = *(const float4*)&Bs[kk][tx * 4];
            acc[0][0] += av.x * bv.x; acc[0][1] += av.x * bv.y;
            acc[0][2] += av.x * bv.z; acc[0][3] += av.x * bv.w;
            acc[1][0] += av.y * bv.x; acc[1][1] += av.y * bv.y;
            acc[1][2] += av.y * bv.z; acc[1][3] += av.y * bv.w;
            acc[2][0] += av.z * bv.x; acc[2][1] += av.z * bv.y;
            acc[2][2] += av.z * bv.z; acc[2][3] += av.z * bv.w;
            acc[3][0] += av.w * bv.x; acc[3][1] += av.w * bv.y;
            acc[3][2] += av.w * bv.z; acc[3][3] += av.w * bv.w;
        }
        __syncthreads();
    }

    float bb_[4];
    #pragma unroll
    for (int jj = 0; jj < 4; ++jj) {
        int gcol = col0 + tx * 4 + jj;
        float bv = 0.f;
        if (gcol < N) {
            int src = gcol;
            if (permGates) {
                int d2 = (gcol >= 400) ? 1 : 0;
                int rr = gcol - d2 * 400;
                src = d2 * 400 + (rr & 3) * 100 + (rr >> 2);
            }
            bv = bias1[src];
            if (bias2) bv += bias2[src];
        }
        bb_[jj] = bv;
    }
    #pragma unroll
    for (int ii = 0; ii < 4; ++ii) {
        int grow = row0 + ty * 4 + ii;
        #pragma unroll
        for (int jj = 0; jj < 4; ++jj) {
            int gcol = col0 + tx * 4 + jj;
            if (gcol < N) C[(size_t)grow * ldc + gcol] = acc[ii][jj] + bb_[jj];
        }
    }
}

// ---------------------------------------------------------------------------
// MFMA LSTM recurrence. 64 blocks = (dir<<5)|b, 448 threads = 7 waves.
// Per step:  G[400] = W_perm[400x128] . h[128]   (bf16 MFMA, K padded)
// W_perm row 4u+q = Whh[dir][q*100+u]; weights live in PHYSICAL AGPRs
// a0..a63 per wave (stashed once; MFMA reads AGPR A-operand at zero cost --
// fixes R3-R6: compiler refused VGPR residency, per-element AGPR reads too
// slow).  h replicated across the 16 B-columns -> every C column equal;
// C layout (col=l&15, row=(l>>4)*4+reg) makes each lane's 4 C regs exactly
// one unit's {i,f,g,o}: activations lane-local, zero shuffles.
// Wave w owns M-tiles 4w..4w+3 (clamped to 24); 25 tiles = 400 gate rows.
// ---------------------------------------------------------------------------
#define STASH_FRAG(DD, F, A0,A1,A2,A3) { \
    int tile = 4*wave + DD; if (tile > 24) tile = 24; \
    int row16 = 16*tile + m16; \
    const float* srcp = Whh + (size_t)(dir*400 + (row16 & 3)*100 + (row16 >> 2)) * HID; \
    const int k0 = 32*F + 8*g4; \
    f32x4 fa = {0.f,0.f,0.f,0.f}, fb = {0.f,0.f,0.f,0.f}; \
    if (k0 < HID) fa = *(const f32x4*)(srcp + k0); \
    if (k0 + 4 < HID) fb = *(const f32x4*)(srcp + k0 + 4); \
    unsigned p0 = bfpack(fa.x, fa.y), p1 = bfpack(fa.z, fa.w); \
    unsigned p2 = bfpack(fb.x, fb.y), p3 = bfpack(fb.z, fb.w); \
    asm volatile("v_accvgpr_write_b32 a" #A0 ", %0\n\t" \
                 "v_accvgpr_write_b32 a" #A1 ", %1\n\t" \
                 "v_accvgpr_write_b32 a" #A2 ", %2\n\t" \
                 "v_accvgpr_write_b32 a" #A3 ", %3" \
                 :: "v"(p0), "v"(p1), "v"(p2), "v"(p3) \
                 : "a" #A0, "a" #A1, "a" #A2, "a" #A3); }

#define MF(ACC, BF, A0, A3) \
    asm volatile("v_mfma_f32_16x16x32_bf16 %0, a[" #A0 ":" #A3 "], %1, %0" \
                 : "+v"(ACC) : "v"(BF));

__global__ __launch_bounds__(448, 1) void lstm_mfma(
    const float* __restrict__ pre,
    const float* __restrict__ Whh,
    float* __restrict__ hout)
{
    const int dir = blockIdx.x >> 5;
    const int b = blockIdx.x & 31;
    const int tid = threadIdx.x;
    const int wave = tid >> 6;          // 0..6
    const int lane = tid & 63;
    const int m16 = lane & 15;          // A row within tile / C column
    const int g4 = lane >> 4;           // k-octet group / C row-group
    const int d = lane & 3;             // designated epilogue fragment

    __shared__ alignas(16) unsigned short h16[2][128];   // bf16 h, K padded to 128

    // ---- one-time stash: 16 A-fragments (4 tiles x 4 k-frags) -> a0..a63 ----
    STASH_FRAG(0,0, 0,1,2,3)    STASH_FRAG(0,1, 4,5,6,7)
    STASH_FRAG(0,2, 8,9,10,11)  STASH_FRAG(0,3, 12,13,14,15)
    STASH_FRAG(1,0, 16,17,18,19) STASH_FRAG(1,1, 20,21,22,23)
    STASH_FRAG(1,2, 24,25,26,27) STASH_FRAG(1,3, 28,29,30,31)
    STASH_FRAG(2,0, 32,33,34,35) STASH_FRAG(2,1, 36,37,38,39)
    STASH_FRAG(2,2, 40,41,42,43) STASH_FRAG(2,3, 44,45,46,47)
    STASH_FRAG(3,0, 48,49,50,51) STASH_FRAG(3,1, 52,53,54,55)
    STASH_FRAG(3,2, 56,57,58,59) STASH_FRAG(3,3, 60,61,62,63)

    if (tid < 128) { h16[0][tid] = 0; h16[1][tid] = 0; }

    // per-thread constants
    int tl0 = 4*wave + 0; if (tl0 > 24) tl0 = 24;
    int tl1 = 4*wave + 1; if (tl1 > 24) tl1 = 24;
    int tl2 = 4*wave + 2; if (tl2 > 24) tl2 = 24;
    int tl3 = 4*wave + 3; if (tl3 > 24) tl3 = 24;
    const int po0 = dir*400 + 16*tl0 + 4*g4;
    const int po1 = dir*400 + 16*tl1 + 4*g4;
    const int po2 = dir*400 + 16*tl2 + 4*g4;
    const int po3 = dir*400 + 16*tl3 + 4*g4;
    int my_tile = 4*wave + d; if (my_tile > 24) my_tile = 24;
    const int my_u = my_tile*4 + g4;                         // 0..99
    const bool writer = ((lane & 12) == 0) && (wave < 6 || d == 0);

    float c = 0.f;
    __syncthreads();

    const int i0 = (dir ? (TT-1) : 0) * BB + b;
    f32x4 pc0 = *(const f32x4*)(pre + (size_t)i0*800 + po0);
    f32x4 pc1 = *(const f32x4*)(pre + (size_t)i0*800 + po1);
    f32x4 pc2 = *(const f32x4*)(pre + (size_t)i0*800 + po2);
    f32x4 pc3 = *(const f32x4*)(pre + (size_t)i0*800 + po3);

    for (int s = 0; s < TT; ++s) {
        const int t = dir ? (TT-1-s) : s;
        const int i = t * BB + b;

        // prefetch next step's pre (used next iteration)
        f32x4 pn0, pn1, pn2, pn3;
        if (s + 1 < TT) {
            const int tn = dir ? (TT-2-s) : (s+1);
            const size_t ib = (size_t)(tn * BB + b) * 800;
            pn0 = *(const f32x4*)(pre + ib + po0);
            pn1 = *(const f32x4*)(pre + ib + po1);
            pn2 = *(const f32x4*)(pre + ib + po2);
            pn3 = *(const f32x4*)(pre + ib + po3);
        } else { pn0 = pc0; pn1 = pc1; pn2 = pc2; pn3 = pc3; }

        // B-fragments: lane needs h16[32f + 8*g4 .. +7] for kfrag f
        const u32x4* hb = (const u32x4*)&h16[s & 1][0];
        u32x4 bf0 = hb[g4];
        u32x4 bf1 = hb[4 + g4];
        u32x4 bf2 = hb[8 + g4];
        u32x4 bf3 = hb[12 + g4];

        f32x4 acc0 = pc0, acc1 = pc1, acc2 = pc2, acc3 = pc3;

        asm volatile("s_nop 1");   // VALU write -> MFMA SrcC read hazard
        MF(acc0, bf0, 0, 3)   MF(acc1, bf0, 16, 19) MF(acc2, bf0, 32, 35) MF(acc3, bf0, 48, 51)
        MF(acc0, bf1, 4, 7)   MF(acc1, bf1, 20, 23) MF(acc2, bf1, 36, 39) MF(acc3, bf1, 52, 55)
        MF(acc0, bf2, 8, 11)  MF(acc1, bf2, 24, 27) MF(acc2, bf2, 40, 43) MF(acc3, bf2, 56, 59)
        MF(acc0, bf3, 12, 15) MF(acc1, bf3, 28, 31) MF(acc2, bf3, 44, 47) MF(acc3, bf3, 60, 63)
        asm volatile("s_nop 7\n\ts_nop 7");  // MFMA write D -> VALU read hazard

        // epilogue: lane's designated frag = one unit's {i,f,g,o}
        f32x4 sel = (d == 0) ? acc0 : (d == 1) ? acc1 : (d == 2) ? acc2 : acc3;
        float igt = sigm(sel.x);
        float fgt = sigm(sel.y);
        float ggt = tanh_(sel.z);
        float ogt = sigm(sel.w);
        c = fgt * c + igt * ggt;
        float h = ogt * tanh_(c);

        if (writer) {
            h16[(s + 1) & 1][my_u] = (unsigned short)bfr(h);
            hout[(size_t)i * 200 + dir * HID + my_u] = h;
        }
        __syncthreads();
        pc0 = pn0; pc1 = pn1; pc2 = pn2; pc3 = pn3;
    }
}

// ---------------------------------------------------------------------------
// logits + log_softmax: one 32-lane half-wave per token.
// ---------------------------------------------------------------------------
__global__ __launch_bounds__(256) void logits_lsm(
    const float* __restrict__ h1,
    const float* __restrict__ out_w,
    const float* __restrict__ out_b,
    float* __restrict__ logits)
{
    const int lane = threadIdx.x & 63;
    const int wid = (blockIdx.x * 256 + threadIdx.x) >> 6;
    const int half = lane >> 5;
    const int n = lane & 31;
    const int i = wid * 2 + half;
    if (i >= NTOK) return;

    float acc = -1e30f;
    if (n < NTAGS) {
        acc = out_b[n];
        const float4* hr = (const float4*)(h1 + (size_t)i * 200);
        const float4* wr = (const float4*)(out_w + (size_t)n * 200);
        #pragma unroll
        for (int e = 0; e < 50; ++e) {
            float4 h4 = hr[e], w4 = wr[e];
            acc += h4.x * w4.x + h4.y * w4.y + h4.z * w4.z + h4.w * w4.w;
        }
    }
    float m = acc;
    for (int off = 16; off > 0; off >>= 1) m = fmaxf(m, __shfl_xor(m, off, 32));
    float ex = (n < NTAGS) ? __expf(acc - m) : 0.f;
    float s = ex;
    for (int off = 16; off > 0; off >>= 1) s += __shfl_xor(s, off, 32);
    if (n < NTAGS) logits[(size_t)i * NTAGS + n] = acc - m - __logf(s);
}

// ---------------------------------------------------------------------------
// CRF loss: one wave per batch element.
// ---------------------------------------------------------------------------
__global__ __launch_bounds__(64) void crf_kernel(
    const float* __restrict__ logits,
    const int* __restrict__ words,
    const int* __restrict__ target,
    const float* __restrict__ trans,
    const float* __restrict__ start_s,
    const float* __restrict__ end_s,
    float* __restrict__ out)
{
    const int b = blockIdx.x;
    const int j = threadIdx.x;

    float tcol[NTAGS];
    #pragma unroll
    for (int i = 0; i < NTAGS; ++i) tcol[i] = (j < NTAGS) ? trans[i * NTAGS + j] : 0.f;

    float alpha = (j < NTAGS) ? (logits[(size_t)(0 * BB + b) * NTAGS + j] + start_s[j]) : -1e30f;

    for (int t = 1; t < TT; ++t) {
        bool mt = (words[b * TT + t] != 0);
        if (mt) {
            float v[NTAGS];
            float mx = -1e30f;
            #pragma unroll
            for (int i2 = 0; i2 < NTAGS; ++i2) {
                float ai = __shfl(alpha, i2, 64);
                v[i2] = ai + tcol[i2];
                mx = fmaxf(mx, v[i2]);
            }
            float s = 0.f;
            #pragma unroll
            for (int i2 = 0; i2 < NTAGS; ++i2) s += __expf(v[i2] - mx);
            float na = mx + __logf(s) + logits[(size_t)(t * BB + b) * NTAGS + j];
            alpha = (j < NTAGS) ? na : -1e30f;
        }
    }

    float val = (j < NTAGS) ? (alpha + end_s[j]) : -1e30f;
    float mx = val;
    for (int off = 32; off > 0; off >>= 1) mx = fmaxf(mx, __shfl_xor(mx, off, 64));
    float s = (j < NTAGS) ? __expf(val - mx) : 0.f;
    for (int off = 32; off > 0; off >>= 1) s += __shfl_xor(s, off, 64);
    float norm = mx + __logf(s);

    float gold = 0.f, slen = 0.f;
    for (int t = j; t < TT; t += 64) {
        int tg = target[b * TT + t];
        bool m = (words[b * TT + t] != 0);
        if (m) {
            gold += logits[(size_t)(t * BB + b) * NTAGS + tg];
            slen += 1.f;
            if (t >= 1) gold += trans[target[b * TT + t - 1] * NTAGS + tg];
        }
    }
    for (int off = 32; off > 0; off >>= 1) {
        gold += __shfl_xor(gold, off, 64);
        slen += __shfl_xor(slen, off, 64);
    }
    if (j == 0) {
        int len = (int)slen;
        int last = (len > 0) ? (len - 1) : 0;
        int last_tag = target[b * TT + last];
        gold += start_s[target[b * TT + 0]] + end_s[last_tag];
        out[b] = norm - gold;
    }
}

// ---------------------------------------------------------------------------
extern "C" void kernel_launch(void* const* d_in, const int* in_sizes, int n_in,
                              void* d_out, int out_size, void* d_ws, size_t ws_size,
                              hipStream_t stream) {
    const int*   words   = (const int*)  d_in[0];
    const int*   target  = (const int*)  d_in[1];
    const float* embed   = (const float*)d_in[2];
    const float* in_fc_w = (const float*)d_in[3];
    const float* in_fc_b = (const float*)d_in[4];
    const float* Wih0    = (const float*)d_in[5];
    const float* Whh0    = (const float*)d_in[6];
    const float* bih0    = (const float*)d_in[7];
    const float* bhh0    = (const float*)d_in[8];
    const float* Wih1    = (const float*)d_in[9];
    const float* Whh1    = (const float*)d_in[10];
    const float* bih1    = (const float*)d_in[11];
    const float* bhh1    = (const float*)d_in[12];
    const float* out_w   = (const float*)d_in[13];
    const float* out_b   = (const float*)d_in[14];
    const float* trans   = (const float*)d_in[15];
    const float* start_s = (const float*)d_in[16];
    const float* end_s   = (const float*)d_in[17];
    float* out = (float*)d_out;

    float* ws = (float*)d_ws;
    // layout (floats): x [0,2097152)  pre [2097152,8650752)  h0 [8650752,10289152)
    //                  h1 = x region  logits [1638400,1810432)
    float* x      = ws;
    float* pre    = ws + 2097152;
    float* h0     = ws + 8650752;
    float* h1     = ws;
    float* logits = ws + 1638400;

    // 1) x = gather(embed, words) @ in_fc_w^T + in_fc_b     (8192 x 256)
    gemm_bias<<<dim3(NTOK / 64, DMODEL / 64), 256, 0, stream>>>(
        embed, EMBED, in_fc_w, EMBED, in_fc_b, nullptr,
        x, DMODEL, NTOK, DMODEL, EMBED, words, 0);

    // 2) pre0 = x @ Wih0^T (gate-permuted) + (bih0 + bhh0)  (8192 x 800)
    gemm_bias<<<dim3(NTOK / 64, 13), 256, 0, stream>>>(
        x, DMODEL, Wih0, DMODEL, bih0, bhh0,
        pre, 800, NTOK, 800, DMODEL, nullptr, 1);

    // 3) layer0 recurrence -> h0 (8192 x 200)
    lstm_mfma<<<64, 448, 0, stream>>>(pre, Whh0, h0);

    // 4) pre1 = h0 @ Wih1^T (gate-permuted) + (bih1 + bhh1) (8192 x 800)
    gemm_bias<<<dim3(NTOK / 64, 13), 256, 0, stream>>>(
        h0, 200, Wih1, 200, bih1, bhh1,
        pre, 800, NTOK, 800, 200, nullptr, 1);

    // 5) layer1 recurrence -> h1 (8192 x 200)
    lstm_mfma<<<64, 448, 0, stream>>>(pre, Whh1, h1);

    // 6) logits + log_softmax (8192 x 21)
    logits_lsm<<<NTOK / 8, 256, 0, stream>>>(h1, out_w, out_b, logits);

    // 7) CRF loss -> out (32)
    crf_kernel<<<BB, 64, 0, stream>>>(logits, words, target, trans, start_s, end_s, out);
}

// Round 8
// 619.020 us; speedup vs baseline: 1.8301x; 1.1097x over previous
//
#include <hip/hip_runtime.h>
#include <hip/hip_bf16.h>

// Model dims
#define VOCAB 21128
#define EMBED 768
#define DMODEL 256
#define HID 100
#define NTAGS 21
#define BB 32
#define TT 256
#define NTOK (BB*TT)   // 8192 tokens, token index i = t*BB + b

typedef float f32x4 __attribute__((ext_vector_type(4)));
typedef unsigned int u32x4 __attribute__((ext_vector_type(4)));
typedef short s16x8 __attribute__((ext_vector_type(8)));

__device__ __forceinline__ float sigm(float x) { return 1.0f / (1.0f + __expf(-x)); }
__device__ __forceinline__ float tanh_(float x) { return 2.0f / (1.0f + __expf(-2.0f * x)) - 1.0f; }

// fp32 -> bf16 with round-to-nearest-even
__device__ __forceinline__ unsigned int bfr(float x) {
    unsigned int u = __float_as_uint(x);
    return (u + 0x7fffu + ((u >> 16) & 1u)) >> 16;
}
__device__ __forceinline__ unsigned int bfpack(float lo, float hi) {
    return (bfr(hi) << 16) | bfr(lo);
}
__device__ __forceinline__ s16x8 asfrag(u32x4 v) {
    union { u32x4 u; s16x8 s; } x; x.u = v; return x.s;
}

// ---------------------------------------------------------------------------
// bf16 MFMA GEMM: C(8192 x N) = A(8192 x K) @ B(N x K)^T + bias (fp32 I/O,
// bf16 fragments, f32 accumulate).  BM=128, BN=64, BK=32, 256 thr = 4 waves,
// wave (wr,wc) owns a 64x32 subtile = 4x2 frags of 16x16.
// LDS layout is MFMA-frag order: [tile16][koctet][lane16][8 bf16] so a full
// wave frag read is ONE contiguous ds_read_b128 per lane (conflict-free).
// gatherWords: A row i -> embed row words[(i&31)*TT + (i>>5)].
// permGates: output col gcol = dir*400 + 4*u + q takes B row / bias from
//   src = dir*400 + q*100 + u (unit-major gate packing for the MFMA LSTM).
// ---------------------------------------------------------------------------
__global__ __launch_bounds__(256) void gemm_mfma(
    const float* __restrict__ A, int lda,
    const float* __restrict__ B, int ldb,
    const float* __restrict__ bias1, const float* __restrict__ bias2,
    float* __restrict__ C, int ldc,
    int N, int K,
    const int* __restrict__ gatherWords, int permGates)
{
    __shared__ unsigned int As_[2][2048];   // 8 tiles x 256 u32 (16 KB total)
    __shared__ unsigned int Bs_[2][1024];   // 4 tiles x 256 u32 (8 KB total)

    const int tid = threadIdx.x;
    const int row0 = blockIdx.x * 128;
    const int col0 = blockIdx.y * 64;
    const int lane = tid & 63;
    const int wave = tid >> 6;
    const int wr = wave >> 1, wc = wave & 1;
    const int nsteps = (K + 31) >> 5;

    // ---- staging descriptors (rows fixed across K-steps) ----
    const float* arow[4]; int aoff[4]; int kqA[4];
    #pragma unroll
    for (int j = 0; j < 4; ++j) {
        int v = tid + 256 * j;
        int row = v >> 3, kq = v & 7;
        int grow = row0 + row;
        const float* ap;
        if (gatherWords) {
            int widx = gatherWords[(grow & 31) * TT + (grow >> 5)];
            ap = A + (size_t)widx * lda;
        } else {
            ap = A + (size_t)grow * lda;
        }
        arow[j] = ap + 4 * kq;
        aoff[j] = (row >> 4) * 256 + (kq >> 1) * 64 + (row & 15) * 4 + (kq & 1) * 2;
        kqA[j] = kq;
    }
    const float* brow[2]; int boff[2]; int bok[2]; int kqB[2];
    #pragma unroll
    for (int j = 0; j < 2; ++j) {
        int v = tid + 256 * j;
        int r = v >> 3, kq = v & 7;
        int gcol = col0 + r;
        bok[j] = (gcol < N);
        int src = bok[j] ? gcol : 0;
        if (permGates && bok[j]) {
            int d2 = (gcol >= 400) ? 1 : 0;
            int rr = gcol - d2 * 400;
            src = d2 * 400 + (rr & 3) * 100 + (rr >> 2);
        }
        brow[j] = B + (size_t)src * ldb + 4 * kq;
        boff[j] = (r >> 4) * 256 + (kq >> 1) * 64 + (r & 15) * 4 + (kq & 1) * 2;
        kqB[j] = kq;
    }

    // prologue: stage step 0 into buffer 0
    {
        #pragma unroll
        for (int j = 0; j < 4; ++j) {
            f32x4 v = {0.f,0.f,0.f,0.f};
            if (4 * kqA[j] < K) v = *(const f32x4*)(arow[j]);
            As_[0][aoff[j]]     = bfpack(v.x, v.y);
            As_[0][aoff[j] + 1] = bfpack(v.z, v.w);
        }
        #pragma unroll
        for (int j = 0; j < 2; ++j) {
            f32x4 v = {0.f,0.f,0.f,0.f};
            if (bok[j] && 4 * kqB[j] < K) v = *(const f32x4*)(brow[j]);
            Bs_[0][boff[j]]     = bfpack(v.x, v.y);
            Bs_[0][boff[j] + 1] = bfpack(v.z, v.w);
        }
    }
    __syncthreads();

    f32x4 acc[4][2] = {};

    for (int s = 0; s < nsteps; ++s) {
        const int cur = s & 1, nxt = cur ^ 1;

        // issue next step's global loads early (hide HBM under MFMA)
        f32x4 la[4], lb[2];
        if (s + 1 < nsteps) {
            const int kb = (s + 1) * 32;
            #pragma unroll
            for (int j = 0; j < 4; ++j) {
                la[j] = (f32x4){0.f,0.f,0.f,0.f};
                if (kb + 4 * kqA[j] < K) la[j] = *(const f32x4*)(arow[j] + kb);
            }
            #pragma unroll
            for (int j = 0; j < 2; ++j) {
                lb[j] = (f32x4){0.f,0.f,0.f,0.f};
                if (bok[j] && kb + 4 * kqB[j] < K) lb[j] = *(const f32x4*)(brow[j] + kb);
            }
        }

        // compute on current buffer
        u32x4 af[4], bf[2];
        #pragma unroll
        for (int mt = 0; mt < 4; ++mt)
            af[mt] = *(const u32x4*)&As_[cur][(4 * wr + mt) * 256 + lane * 4];
        #pragma unroll
        for (int nt = 0; nt < 2; ++nt)
            bf[nt] = *(const u32x4*)&Bs_[cur][(2 * wc + nt) * 256 + lane * 4];
        #pragma unroll
        for (int mt = 0; mt < 4; ++mt)
            #pragma unroll
            for (int nt = 0; nt < 2; ++nt)
                acc[mt][nt] = __builtin_amdgcn_mfma_f32_16x16x32_bf16(
                    asfrag(af[mt]), asfrag(bf[nt]), acc[mt][nt], 0, 0, 0);

        // write next step's tiles (other buffer), then one barrier
        if (s + 1 < nsteps) {
            #pragma unroll
            for (int j = 0; j < 4; ++j) {
                As_[nxt][aoff[j]]     = bfpack(la[j].x, la[j].y);
                As_[nxt][aoff[j] + 1] = bfpack(la[j].z, la[j].w);
            }
            #pragma unroll
            for (int j = 0; j < 2; ++j) {
                Bs_[nxt][boff[j]]     = bfpack(lb[j].x, lb[j].y);
                Bs_[nxt][boff[j] + 1] = bfpack(lb[j].z, lb[j].w);
            }
        }
        __syncthreads();
    }

    // epilogue: bias + store (C col = lane&15, row = (lane>>4)*4 + reg)
    const int r4 = (lane >> 4) * 4;
    const int cl = lane & 15;
    #pragma unroll
    for (int nt = 0; nt < 2; ++nt) {
        int gcol = col0 + (2 * wc + nt) * 16 + cl;
        if (gcol < N) {
            int src = gcol;
            if (permGates) {
                int d2 = (gcol >= 400) ? 1 : 0;
                int rr = gcol - d2 * 400;
                src = d2 * 400 + (rr & 3) * 100 + (rr >> 2);
            }
            float bv = bias1[src];
            if (bias2) bv += bias2[src];
            #pragma unroll
            for (int mt = 0; mt < 4; ++mt) {
                int grow = row0 + (4 * wr + mt) * 16 + r4;
                #pragma unroll
                for (int r = 0; r < 4; ++r)
                    C[(size_t)(grow + r) * ldc + gcol] = acc[mt][nt][r] + bv;
            }
        }
    }
}

// ---------------------------------------------------------------------------
// MFMA LSTM recurrence. 64 blocks = (dir<<5)|b, 448 threads = 7 waves.
// Weights in PHYSICAL AGPRs a0..a63 (A-operand, zero per-use cost); h
// replicated across B-columns; C layout makes each lane's 4 C regs one
// unit's {i,f,g,o} -> lane-local activations, zero shuffles.
// R7 lesson: pre streams from HBM (~900 cyc); 1-step prefetch left ~800
// cyc/step exposed (180 us, MfmaUtil 6.5%).  Now 2-step-deep prefetch via
// ping-pong register slots pa/pb: issue->consume distance ~2 steps.
// ---------------------------------------------------------------------------
#define STASH_FRAG(DD, F, A0,A1,A2,A3) { \
    int tile = 4*wave + DD; if (tile > 24) tile = 24; \
    int row16 = 16*tile + m16; \
    const float* srcp = Whh + (size_t)(dir*400 + (row16 & 3)*100 + (row16 >> 2)) * HID; \
    const int k0 = 32*F + 8*g4; \
    f32x4 fa = {0.f,0.f,0.f,0.f}, fb = {0.f,0.f,0.f,0.f}; \
    if (k0 < HID) fa = *(const f32x4*)(srcp + k0); \
    if (k0 + 4 < HID) fb = *(const f32x4*)(srcp + k0 + 4); \
    unsigned p0 = bfpack(fa.x, fa.y), p1 = bfpack(fa.z, fa.w); \
    unsigned p2 = bfpack(fb.x, fb.y), p3 = bfpack(fb.z, fb.w); \
    asm volatile("v_accvgpr_write_b32 a" #A0 ", %0\n\t" \
                 "v_accvgpr_write_b32 a" #A1 ", %1\n\t" \
                 "v_accvgpr_write_b32 a" #A2 ", %2\n\t" \
                 "v_accvgpr_write_b32 a" #A3 ", %3" \
                 :: "v"(p0), "v"(p1), "v"(p2), "v"(p3) \
                 : "a" #A0, "a" #A1, "a" #A2, "a" #A3); }

#define MF(ACC, BF, A0, A3) \
    asm volatile("v_mfma_f32_16x16x32_bf16 %0, a[" #A0 ":" #A3 "], %1, %0" \
                 : "+v"(ACC) : "v"(BF));

#define LSTM_STEP(P0,P1,P2,P3, S) { \
    const int t_ = dir ? (TT-1-(S)) : (S); \
    const int i_ = t_ * BB + b; \
    const u32x4* hb_ = (const u32x4*)&h16[(S) & 1][0]; \
    u32x4 bf0 = hb_[g4], bf1 = hb_[4+g4], bf2 = hb_[8+g4], bf3 = hb_[12+g4]; \
    f32x4 acc0 = P0, acc1 = P1, acc2 = P2, acc3 = P3; \
    if ((S) + 2 < TT) { \
        const int tn_ = dir ? (TT-3-(S)) : ((S)+2); \
        const size_t ib_ = (size_t)(tn_ * BB + b) * 800; \
        P0 = *(const f32x4*)(pre + ib_ + po0); \
        P1 = *(const f32x4*)(pre + ib_ + po1); \
        P2 = *(const f32x4*)(pre + ib_ + po2); \
        P3 = *(const f32x4*)(pre + ib_ + po3); \
    } \
    asm volatile("s_nop 1"); \
    MF(acc0, bf0, 0, 3)   MF(acc1, bf0, 16, 19) MF(acc2, bf0, 32, 35) MF(acc3, bf0, 48, 51) \
    MF(acc0, bf1, 4, 7)   MF(acc1, bf1, 20, 23) MF(acc2, bf1, 36, 39) MF(acc3, bf1, 52, 55) \
    MF(acc0, bf2, 8, 11)  MF(acc1, bf2, 24, 27) MF(acc2, bf2, 40, 43) MF(acc3, bf2, 56, 59) \
    MF(acc0, bf3, 12, 15) MF(acc1, bf3, 28, 31) MF(acc2, bf3, 44, 47) MF(acc3, bf3, 60, 63) \
    asm volatile("s_nop 7\n\ts_nop 7"); \
    f32x4 sel = (d == 0) ? acc0 : (d == 1) ? acc1 : (d == 2) ? acc2 : acc3; \
    float igt = sigm(sel.x); \
    float fgt = sigm(sel.y); \
    float ggt = tanh_(sel.z); \
    float ogt = sigm(sel.w); \
    c = fgt * c + igt * ggt; \
    float h = ogt * tanh_(c); \
    if (writer) { \
        h16[((S) + 1) & 1][my_u] = (unsigned short)bfr(h); \
        hout[(size_t)i_ * 200 + dir * HID + my_u] = h; \
    } \
    __syncthreads(); }

__global__ __launch_bounds__(448, 1) void lstm_mfma(
    const float* __restrict__ pre,
    const float* __restrict__ Whh,
    float* __restrict__ hout)
{
    const int dir = blockIdx.x >> 5;
    const int b = blockIdx.x & 31;
    const int tid = threadIdx.x;
    const int wave = tid >> 6;          // 0..6
    const int lane = tid & 63;
    const int m16 = lane & 15;          // A row within tile / C column
    const int g4 = lane >> 4;           // k-octet group / C row-group
    const int d = lane & 3;             // designated epilogue fragment

    __shared__ alignas(16) unsigned short h16[2][128];   // bf16 h, K padded to 128

    // one-time stash: 16 A-fragments (4 tiles x 4 k-frags) -> a0..a63
    STASH_FRAG(0,0, 0,1,2,3)    STASH_FRAG(0,1, 4,5,6,7)
    STASH_FRAG(0,2, 8,9,10,11)  STASH_FRAG(0,3, 12,13,14,15)
    STASH_FRAG(1,0, 16,17,18,19) STASH_FRAG(1,1, 20,21,22,23)
    STASH_FRAG(1,2, 24,25,26,27) STASH_FRAG(1,3, 28,29,30,31)
    STASH_FRAG(2,0, 32,33,34,35) STASH_FRAG(2,1, 36,37,38,39)
    STASH_FRAG(2,2, 40,41,42,43) STASH_FRAG(2,3, 44,45,46,47)
    STASH_FRAG(3,0, 48,49,50,51) STASH_FRAG(3,1, 52,53,54,55)
    STASH_FRAG(3,2, 56,57,58,59) STASH_FRAG(3,3, 60,61,62,63)

    if (tid < 128) { h16[0][tid] = 0; h16[1][tid] = 0; }

    int tl0 = 4*wave + 0; if (tl0 > 24) tl0 = 24;
    int tl1 = 4*wave + 1; if (tl1 > 24) tl1 = 24;
    int tl2 = 4*wave + 2; if (tl2 > 24) tl2 = 24;
    int tl3 = 4*wave + 3; if (tl3 > 24) tl3 = 24;
    const int po0 = dir*400 + 16*tl0 + 4*g4;
    const int po1 = dir*400 + 16*tl1 + 4*g4;
    const int po2 = dir*400 + 16*tl2 + 4*g4;
    const int po3 = dir*400 + 16*tl3 + 4*g4;
    int my_tile = 4*wave + d; if (my_tile > 24) my_tile = 24;
    const int my_u = my_tile*4 + g4;                         // 0..99
    const bool writer = ((lane & 12) == 0) && (wave < 6 || d == 0);

    float c = 0.f;
    __syncthreads();

    // 2-deep prologue: slots pa (step 0), pb (step 1)
    const size_t ib0 = (size_t)((dir ? (TT-1) : 0) * BB + b) * 800;
    const size_t ib1 = (size_t)((dir ? (TT-2) : 1) * BB + b) * 800;
    f32x4 pa0 = *(const f32x4*)(pre + ib0 + po0);
    f32x4 pa1 = *(const f32x4*)(pre + ib0 + po1);
    f32x4 pa2 = *(const f32x4*)(pre + ib0 + po2);
    f32x4 pa3 = *(const f32x4*)(pre + ib0 + po3);
    f32x4 pb0 = *(const f32x4*)(pre + ib1 + po0);
    f32x4 pb1 = *(const f32x4*)(pre + ib1 + po1);
    f32x4 pb2 = *(const f32x4*)(pre + ib1 + po2);
    f32x4 pb3 = *(const f32x4*)(pre + ib1 + po3);

    for (int s = 0; s < TT; s += 2) {
        LSTM_STEP(pa0, pa1, pa2, pa3, s)
        LSTM_STEP(pb0, pb1, pb2, pb3, s + 1)
    }
}

// ---------------------------------------------------------------------------
// logits + log_softmax: one 32-lane half-wave per token.
// ---------------------------------------------------------------------------
__global__ __launch_bounds__(256) void logits_lsm(
    const float* __restrict__ h1,
    const float* __restrict__ out_w,
    const float* __restrict__ out_b,
    float* __restrict__ logits)
{
    const int lane = threadIdx.x & 63;
    const int wid = (blockIdx.x * 256 + threadIdx.x) >> 6;
    const int half = lane >> 5;
    const int n = lane & 31;
    const int i = wid * 2 + half;
    if (i >= NTOK) return;

    float acc = -1e30f;
    if (n < NTAGS) {
        acc = out_b[n];
        const float4* hr = (const float4*)(h1 + (size_t)i * 200);
        const float4* wr = (const float4*)(out_w + (size_t)n * 200);
        #pragma unroll
        for (int e = 0; e < 50; ++e) {
            float4 h4 = hr[e], w4 = wr[e];
            acc += h4.x * w4.x + h4.y * w4.y + h4.z * w4.z + h4.w * w4.w;
        }
    }
    float m = acc;
    for (int off = 16; off > 0; off >>= 1) m = fmaxf(m, __shfl_xor(m, off, 32));
    float ex = (n < NTAGS) ? __expf(acc - m) : 0.f;
    float s = ex;
    for (int off = 16; off > 0; off >>= 1) s += __shfl_xor(s, off, 32);
    if (n < NTAGS) logits[(size_t)i * NTAGS + n] = acc - m - __logf(s);
}

// ---------------------------------------------------------------------------
// CRF loss: one wave per batch element.
// ---------------------------------------------------------------------------
__global__ __launch_bounds__(64) void crf_kernel(
    const float* __restrict__ logits,
    const int* __restrict__ words,
    const int* __restrict__ target,
    const float* __restrict__ trans,
    const float* __restrict__ start_s,
    const float* __restrict__ end_s,
    float* __restrict__ out)
{
    const int b = blockIdx.x;
    const int j = threadIdx.x;

    float tcol[NTAGS];
    #pragma unroll
    for (int i = 0; i < NTAGS; ++i) tcol[i] = (j < NTAGS) ? trans[i * NTAGS + j] : 0.f;

    float alpha = (j < NTAGS) ? (logits[(size_t)(0 * BB + b) * NTAGS + j] + start_s[j]) : -1e30f;

    for (int t = 1; t < TT; ++t) {
        bool mt = (words[b * TT + t] != 0);
        if (mt) {
            float v[NTAGS];
            float mx = -1e30f;
            #pragma unroll
            for (int i2 = 0; i2 < NTAGS; ++i2) {
                float ai = __shfl(alpha, i2, 64);
                v[i2] = ai + tcol[i2];
                mx = fmaxf(mx, v[i2]);
            }
            float s = 0.f;
            #pragma unroll
            for (int i2 = 0; i2 < NTAGS; ++i2) s += __expf(v[i2] - mx);
            float na = mx + __logf(s) + logits[(size_t)(t * BB + b) * NTAGS + j];
            alpha = (j < NTAGS) ? na : -1e30f;
        }
    }

    float val = (j < NTAGS) ? (alpha + end_s[j]) : -1e30f;
    float mx = val;
    for (int off = 32; off > 0; off >>= 1) mx = fmaxf(mx, __shfl_xor(mx, off, 64));
    float s = (j < NTAGS) ? __expf(val - mx) : 0.f;
    for (int off = 32; off > 0; off >>= 1) s += __shfl_xor(s, off, 64);
    float norm = mx + __logf(s);

    float gold = 0.f, slen = 0.f;
    for (int t = j; t < TT; t += 64) {
        int tg = target[b * TT + t];
        bool m = (words[b * TT + t] != 0);
        if (m) {
            gold += logits[(size_t)(t * BB + b) * NTAGS + tg];
            slen += 1.f;
            if (t >= 1) gold += trans[target[b * TT + t - 1] * NTAGS + tg];
        }
    }
    for (int off = 32; off > 0; off >>= 1) {
        gold += __shfl_xor(gold, off, 64);
        slen += __shfl_xor(slen, off, 64);
    }
    if (j == 0) {
        int len = (int)slen;
        int last = (len > 0) ? (len - 1) : 0;
        int last_tag = target[b * TT + last];
        gold += start_s[target[b * TT + 0]] + end_s[last_tag];
        out[b] = norm - gold;
    }
}

// ---------------------------------------------------------------------------
extern "C" void kernel_launch(void* const* d_in, const int* in_sizes, int n_in,
                              void* d_out, int out_size, void* d_ws, size_t ws_size,
                              hipStream_t stream) {
    const int*   words   = (const int*)  d_in[0];
    const int*   target  = (const int*)  d_in[1];
    const float* embed   = (const float*)d_in[2];
    const float* in_fc_w = (const float*)d_in[3];
    const float* in_fc_b = (const float*)d_in[4];
    const float* Wih0    = (const float*)d_in[5];
    const float* Whh0    = (const float*)d_in[6];
    const float* bih0    = (const float*)d_in[7];
    const float* bhh0    = (const float*)d_in[8];
    const float* Wih1    = (const float*)d_in[9];
    const float* Whh1    = (const float*)d_in[10];
    const float* bih1    = (const float*)d_in[11];
    const float* bhh1    = (const float*)d_in[12];
    const float* out_w   = (const float*)d_in[13];
    const float* out_b   = (const float*)d_in[14];
    const float* trans   = (const float*)d_in[15];
    const float* start_s = (const float*)d_in[16];
    const float* end_s   = (const float*)d_in[17];
    float* out = (float*)d_out;

    float* ws = (float*)d_ws;
    // layout (floats): x [0,2097152)  pre [2097152,8650752)  h0 [8650752,10289152)
    //                  h1 = x region  logits [1638400,1810432)
    float* x      = ws;
    float* pre    = ws + 2097152;
    float* h0     = ws + 8650752;
    float* h1     = ws;
    float* logits = ws + 1638400;

    // 1) x = gather(embed, words) @ in_fc_w^T + in_fc_b     (8192 x 256)
    gemm_mfma<<<dim3(64, 4), 256, 0, stream>>>(
        embed, EMBED, in_fc_w, EMBED, in_fc_b, nullptr,
        x, DMODEL, DMODEL, EMBED, words, 0);

    // 2) pre0 = x @ Wih0^T (gate-permuted) + (bih0 + bhh0)  (8192 x 800)
    gemm_mfma<<<dim3(64, 13), 256, 0, stream>>>(
        x, DMODEL, Wih0, DMODEL, bih0, bhh0,
        pre, 800, 800, DMODEL, nullptr, 1);

    // 3) layer0 recurrence -> h0 (8192 x 200)
    lstm_mfma<<<64, 448, 0, stream>>>(pre, Whh0, h0);

    // 4) pre1 = h0 @ Wih1^T (gate-permuted) + (bih1 + bhh1) (8192 x 800)
    gemm_mfma<<<dim3(64, 13), 256, 0, stream>>>(
        h0, 200, Wih1, 200, bih1, bhh1,
        pre, 800, 800, 200, nullptr, 1);

    // 5) layer1 recurrence -> h1 (8192 x 200)
    lstm_mfma<<<64, 448, 0, stream>>>(pre, Whh1, h1);

    // 6) logits + log_softmax (8192 x 21)
    logits_lsm<<<NTOK / 8, 256, 0, stream>>>(h1, out_w, out_b, logits);

    // 7) CRF loss -> out (32)
    crf_kernel<<<BB, 64, 0, stream>>>(logits, words, target, trans, start_s, end_s, out);
}

// Round 9
// 580.578 us; speedup vs baseline: 1.9513x; 1.0662x over previous
//
#include <hip/hip_runtime.h>
#include <hip/hip_bf16.h>

// Model dims
#define VOCAB 21128
#define EMBED 768
#define DMODEL 256
#define HID 100
#define NTAGS 21
#define BB 32
#define TT 256
#define NTOK (BB*TT)   // 8192 tokens, token index i = t*BB + b

typedef float f32x4 __attribute__((ext_vector_type(4)));
typedef unsigned int u32x4 __attribute__((ext_vector_type(4)));
typedef short s16x8 __attribute__((ext_vector_type(8)));

__device__ __forceinline__ float sigm(float x) { return 1.0f / (1.0f + __expf(-x)); }
__device__ __forceinline__ float tanh_(float x) { return 2.0f / (1.0f + __expf(-2.0f * x)) - 1.0f; }

// fp32 -> bf16 with round-to-nearest-even
__device__ __forceinline__ unsigned int bfr(float x) {
    unsigned int u = __float_as_uint(x);
    return (u + 0x7fffu + ((u >> 16) & 1u)) >> 16;
}
__device__ __forceinline__ unsigned int bfpack(float lo, float hi) {
    return (bfr(hi) << 16) | bfr(lo);
}
__device__ __forceinline__ s16x8 asfrag(u32x4 v) {
    union { u32x4 u; s16x8 s; } x; x.u = v; return x.s;
}

// Raw barrier: fence LDS only; vmem ops RIDE ACROSS (no vmcnt(0) drain --
// __syncthreads() drains all outstanding global loads/stores, which was
// exposing ~900 cyc of HBM latency per LSTM step in R7/R8).
#define BAR() do { \
    asm volatile("s_waitcnt lgkmcnt(0)" ::: "memory"); \
    __builtin_amdgcn_s_barrier(); \
    __builtin_amdgcn_sched_barrier(0); \
} while (0)

// ---------------------------------------------------------------------------
// bf16 MFMA GEMM: C(8192 x N) = A(8192 x K) @ B(N x K)^T + bias (fp32 I/O,
// bf16 fragments, f32 accumulate).  BM=128, BN=64, BK=32, 256 thr = 4 waves.
// ---------------------------------------------------------------------------
__global__ __launch_bounds__(256) void gemm_mfma(
    const float* __restrict__ A, int lda,
    const float* __restrict__ B, int ldb,
    const float* __restrict__ bias1, const float* __restrict__ bias2,
    float* __restrict__ C, int ldc,
    int N, int K,
    const int* __restrict__ gatherWords, int permGates)
{
    __shared__ unsigned int As_[2][2048];
    __shared__ unsigned int Bs_[2][1024];

    const int tid = threadIdx.x;
    const int row0 = blockIdx.x * 128;
    const int col0 = blockIdx.y * 64;
    const int lane = tid & 63;
    const int wave = tid >> 6;
    const int wr = wave >> 1, wc = wave & 1;
    const int nsteps = (K + 31) >> 5;

    const float* arow[4]; int aoff[4]; int kqA[4];
    #pragma unroll
    for (int j = 0; j < 4; ++j) {
        int v = tid + 256 * j;
        int row = v >> 3, kq = v & 7;
        int grow = row0 + row;
        const float* ap;
        if (gatherWords) {
            int widx = gatherWords[(grow & 31) * TT + (grow >> 5)];
            ap = A + (size_t)widx * lda;
        } else {
            ap = A + (size_t)grow * lda;
        }
        arow[j] = ap + 4 * kq;
        aoff[j] = (row >> 4) * 256 + (kq >> 1) * 64 + (row & 15) * 4 + (kq & 1) * 2;
        kqA[j] = kq;
    }
    const float* brow[2]; int boff[2]; int bok[2]; int kqB[2];
    #pragma unroll
    for (int j = 0; j < 2; ++j) {
        int v = tid + 256 * j;
        int r = v >> 3, kq = v & 7;
        int gcol = col0 + r;
        bok[j] = (gcol < N);
        int src = bok[j] ? gcol : 0;
        if (permGates && bok[j]) {
            int d2 = (gcol >= 400) ? 1 : 0;
            int rr = gcol - d2 * 400;
            src = d2 * 400 + (rr & 3) * 100 + (rr >> 2);
        }
        brow[j] = B + (size_t)src * ldb + 4 * kq;
        boff[j] = (r >> 4) * 256 + (kq >> 1) * 64 + (r & 15) * 4 + (kq & 1) * 2;
        kqB[j] = kq;
    }

    {
        #pragma unroll
        for (int j = 0; j < 4; ++j) {
            f32x4 v = {0.f,0.f,0.f,0.f};
            if (4 * kqA[j] < K) v = *(const f32x4*)(arow[j]);
            As_[0][aoff[j]]     = bfpack(v.x, v.y);
            As_[0][aoff[j] + 1] = bfpack(v.z, v.w);
        }
        #pragma unroll
        for (int j = 0; j < 2; ++j) {
            f32x4 v = {0.f,0.f,0.f,0.f};
            if (bok[j] && 4 * kqB[j] < K) v = *(const f32x4*)(brow[j]);
            Bs_[0][boff[j]]     = bfpack(v.x, v.y);
            Bs_[0][boff[j] + 1] = bfpack(v.z, v.w);
        }
    }
    BAR();

    f32x4 acc[4][2] = {};

    for (int s = 0; s < nsteps; ++s) {
        const int cur = s & 1, nxt = cur ^ 1;

        f32x4 la[4], lb[2];
        if (s + 1 < nsteps) {
            const int kb = (s + 1) * 32;
            #pragma unroll
            for (int j = 0; j < 4; ++j) {
                la[j] = (f32x4){0.f,0.f,0.f,0.f};
                if (kb + 4 * kqA[j] < K) la[j] = *(const f32x4*)(arow[j] + kb);
            }
            #pragma unroll
            for (int j = 0; j < 2; ++j) {
                lb[j] = (f32x4){0.f,0.f,0.f,0.f};
                if (bok[j] && kb + 4 * kqB[j] < K) lb[j] = *(const f32x4*)(brow[j] + kb);
            }
        }

        u32x4 af[4], bf[2];
        #pragma unroll
        for (int mt = 0; mt < 4; ++mt)
            af[mt] = *(const u32x4*)&As_[cur][(4 * wr + mt) * 256 + lane * 4];
        #pragma unroll
        for (int nt = 0; nt < 2; ++nt)
            bf[nt] = *(const u32x4*)&Bs_[cur][(2 * wc + nt) * 256 + lane * 4];
        #pragma unroll
        for (int mt = 0; mt < 4; ++mt)
            #pragma unroll
            for (int nt = 0; nt < 2; ++nt)
                acc[mt][nt] = __builtin_amdgcn_mfma_f32_16x16x32_bf16(
                    asfrag(af[mt]), asfrag(bf[nt]), acc[mt][nt], 0, 0, 0);

        if (s + 1 < nsteps) {
            #pragma unroll
            for (int j = 0; j < 4; ++j) {
                As_[nxt][aoff[j]]     = bfpack(la[j].x, la[j].y);
                As_[nxt][aoff[j] + 1] = bfpack(la[j].z, la[j].w);
            }
            #pragma unroll
            for (int j = 0; j < 2; ++j) {
                Bs_[nxt][boff[j]]     = bfpack(lb[j].x, lb[j].y);
                Bs_[nxt][boff[j] + 1] = bfpack(lb[j].z, lb[j].w);
            }
        }
        BAR();
    }

    const int r4 = (lane >> 4) * 4;
    const int cl = lane & 15;
    #pragma unroll
    for (int nt = 0; nt < 2; ++nt) {
        int gcol = col0 + (2 * wc + nt) * 16 + cl;
        if (gcol < N) {
            int src = gcol;
            if (permGates) {
                int d2 = (gcol >= 400) ? 1 : 0;
                int rr = gcol - d2 * 400;
                src = d2 * 400 + (rr & 3) * 100 + (rr >> 2);
            }
            float bv = bias1[src];
            if (bias2) bv += bias2[src];
            #pragma unroll
            for (int mt = 0; mt < 4; ++mt) {
                int grow = row0 + (4 * wr + mt) * 16 + r4;
                #pragma unroll
                for (int r = 0; r < 4; ++r)
                    C[(size_t)(grow + r) * ldc + gcol] = acc[mt][nt][r] + bv;
            }
        }
    }
}

// ---------------------------------------------------------------------------
// MFMA LSTM recurrence. 64 blocks = (dir<<5)|b, 448 threads = 7 waves.
// Weights in PHYSICAL AGPRs a0..a63 (MFMA A-operand).  R8 lesson: the
// __syncthreads vmcnt(0) drain exposed ~900 cyc HBM latency per step.
// Now: (a) raw lgkmcnt-only barriers (BAR), (b) pre staged into LDS in
// 16-step chunks, double-buffered, loads issued one full chunk (~6000 cyc)
// ahead -> latency hidden with counted waits, (c) acc starts at 0 and pre
// is folded into the epilogue (only the designated fragment is consumed):
// 1 ds_read_b128 of pre per lane per step instead of 4.
// ---------------------------------------------------------------------------
#define STASH_FRAG(DD, F, A0,A1,A2,A3) { \
    int tile = 4*wave + DD; if (tile > 24) tile = 24; \
    int row16 = 16*tile + m16; \
    const float* srcp = Whh + (size_t)(dir*400 + (row16 & 3)*100 + (row16 >> 2)) * HID; \
    const int k0 = 32*F + 8*g4; \
    f32x4 fa = {0.f,0.f,0.f,0.f}, fb = {0.f,0.f,0.f,0.f}; \
    if (k0 < HID) fa = *(const f32x4*)(srcp + k0); \
    if (k0 + 4 < HID) fb = *(const f32x4*)(srcp + k0 + 4); \
    unsigned p0 = bfpack(fa.x, fa.y), p1 = bfpack(fa.z, fa.w); \
    unsigned p2 = bfpack(fb.x, fb.y), p3 = bfpack(fb.z, fb.w); \
    asm volatile("v_accvgpr_write_b32 a" #A0 ", %0\n\t" \
                 "v_accvgpr_write_b32 a" #A1 ", %1\n\t" \
                 "v_accvgpr_write_b32 a" #A2 ", %2\n\t" \
                 "v_accvgpr_write_b32 a" #A3 ", %3" \
                 :: "v"(p0), "v"(p1), "v"(p2), "v"(p3) \
                 : "a" #A0, "a" #A1, "a" #A2, "a" #A3); }

#define MF(ACC, BF, A0, A3) \
    asm volatile("v_mfma_f32_16x16x32_bf16 %0, a[" #A0 ":" #A3 "], %1, %0" \
                 : "+v"(ACC) : "v"(BF));

#define LOADCHUNK(K2) { \
    const int s0_ = 16 * (K2); \
    _Pragma("unroll") \
    for (int j = 0; j < 4; ++j) { \
        if (okj[j]) { \
            int tg = dir ? (TT - 1 - (s0_ + sicj[j])) : (s0_ + sicj[j]); \
            rr[j] = *(const f32x4*)(pre + (size_t)(tg * BB + b) * 800 + dir * 400 + 4 * gqj[j]); \
        } \
    } }

#define WRITECHUNK(BUF) { \
    _Pragma("unroll") \
    for (int j = 0; j < 4; ++j) { \
        if (okj[j]) *(f32x4*)&preS[(BUF) * 6400 + sicj[j] * 400 + 4 * gqj[j]] = rr[j]; \
    } }

#define LSTM_STEP(SIC) { \
    const int t_ = dir ? (TT - 1 - (s0 + (SIC))) : (s0 + (SIC)); \
    const u32x4* hb_ = (const u32x4*)&h16[(SIC) & 1][0]; \
    u32x4 bf0 = hb_[g4], bf1 = hb_[4+g4], bf2 = hb_[8+g4], bf3 = hb_[12+g4]; \
    f32x4 p4 = *(const f32x4*)&preS[curbase + (SIC) * 400 + my_po]; \
    f32x4 acc0 = {0.f,0.f,0.f,0.f}, acc1 = {0.f,0.f,0.f,0.f}; \
    f32x4 acc2 = {0.f,0.f,0.f,0.f}, acc3 = {0.f,0.f,0.f,0.f}; \
    asm volatile("s_nop 1"); \
    MF(acc0, bf0, 0, 3)   MF(acc1, bf0, 16, 19) MF(acc2, bf0, 32, 35) MF(acc3, bf0, 48, 51) \
    MF(acc0, bf1, 4, 7)   MF(acc1, bf1, 20, 23) MF(acc2, bf1, 36, 39) MF(acc3, bf1, 52, 55) \
    MF(acc0, bf2, 8, 11)  MF(acc1, bf2, 24, 27) MF(acc2, bf2, 40, 43) MF(acc3, bf2, 56, 59) \
    MF(acc0, bf3, 12, 15) MF(acc1, bf3, 28, 31) MF(acc2, bf3, 44, 47) MF(acc3, bf3, 60, 63) \
    asm volatile("s_nop 7\n\ts_nop 7"); \
    f32x4 sel = (d == 0) ? acc0 : (d == 1) ? acc1 : (d == 2) ? acc2 : acc3; \
    float igt = sigm(sel.x + p4.x); \
    float fgt = sigm(sel.y + p4.y); \
    float ggt = tanh_(sel.z + p4.z); \
    float ogt = sigm(sel.w + p4.w); \
    c = fgt * c + igt * ggt; \
    float h = ogt * tanh_(c); \
    if (writer) { \
        h16[((SIC) + 1) & 1][my_u] = (unsigned short)bfr(h); \
        hout[(size_t)(t_ * BB + b) * 200 + dir * HID + my_u] = h; \
    } \
    BAR(); }

__global__ __launch_bounds__(448, 1) void lstm_mfma(
    const float* __restrict__ pre,
    const float* __restrict__ Whh,
    float* __restrict__ hout)
{
    const int dir = blockIdx.x >> 5;
    const int b = blockIdx.x & 31;
    const int tid = threadIdx.x;
    const int wave = tid >> 6;          // 0..6
    const int lane = tid & 63;
    const int m16 = lane & 15;
    const int g4 = lane >> 4;           // k-octet group / C row-group
    const int d = lane & 3;             // designated epilogue fragment

    __shared__ alignas(16) unsigned short h16[2][128];
    __shared__ alignas(16) float preS[2 * 6400];   // 2 x 16 steps x 400 gates

    // one-time stash: 16 A-fragments -> a0..a63
    STASH_FRAG(0,0, 0,1,2,3)    STASH_FRAG(0,1, 4,5,6,7)
    STASH_FRAG(0,2, 8,9,10,11)  STASH_FRAG(0,3, 12,13,14,15)
    STASH_FRAG(1,0, 16,17,18,19) STASH_FRAG(1,1, 20,21,22,23)
    STASH_FRAG(1,2, 24,25,26,27) STASH_FRAG(1,3, 28,29,30,31)
    STASH_FRAG(2,0, 32,33,34,35) STASH_FRAG(2,1, 36,37,38,39)
    STASH_FRAG(2,2, 40,41,42,43) STASH_FRAG(2,3, 44,45,46,47)
    STASH_FRAG(3,0, 48,49,50,51) STASH_FRAG(3,1, 52,53,54,55)
    STASH_FRAG(3,2, 56,57,58,59) STASH_FRAG(3,3, 60,61,62,63)

    if (tid < 128) { h16[0][tid] = 0; h16[1][tid] = 0; }

    int my_tile = 4 * wave + d; if (my_tile > 24) my_tile = 24;
    const int my_u = my_tile * 4 + g4;                       // 0..99
    const int my_po = 16 * my_tile + 4 * g4;                 // pre offset (floats)
    const bool writer = ((lane & 12) == 0) && (wave < 6 || d == 0);

    // chunk staging descriptors: 1600 f32x4 per chunk over 448 threads
    int sicj[4], gqj[4]; bool okj[4];
    #pragma unroll
    for (int j = 0; j < 4; ++j) {
        int idx = tid + 448 * j;
        okj[j] = (idx < 1600);
        int ic = okj[j] ? idx : 0;
        sicj[j] = ic / 100;
        gqj[j] = ic - 100 * sicj[j];
    }

    float c = 0.f;
    f32x4 rr[4];

    // prologue: chunk 0 -> LDS[0]; issue chunk 1 loads
    LOADCHUNK(0)
    WRITECHUNK(0)
    LOADCHUNK(1)
    BAR();

    for (int k = 0; k < 16; ++k) {
        const int s0 = 16 * k;
        const int curbase = (k & 1) * 6400;
        LSTM_STEP(0)  LSTM_STEP(1)  LSTM_STEP(2)  LSTM_STEP(3)
        LSTM_STEP(4)  LSTM_STEP(5)  LSTM_STEP(6)  LSTM_STEP(7)
        LSTM_STEP(8)  LSTM_STEP(9)  LSTM_STEP(10) LSTM_STEP(11)
        LSTM_STEP(12) LSTM_STEP(13) LSTM_STEP(14) LSTM_STEP(15)
        if (k < 15) { WRITECHUNK((k & 1) ^ 1) }
        if (k < 14) { LOADCHUNK(k + 2) }
        BAR();
    }
}

// ---------------------------------------------------------------------------
// logits + log_softmax: one 32-lane half-wave per token.
// ---------------------------------------------------------------------------
__global__ __launch_bounds__(256) void logits_lsm(
    const float* __restrict__ h1,
    const float* __restrict__ out_w,
    const float* __restrict__ out_b,
    float* __restrict__ logits)
{
    const int lane = threadIdx.x & 63;
    const int wid = (blockIdx.x * 256 + threadIdx.x) >> 6;
    const int half = lane >> 5;
    const int n = lane & 31;
    const int i = wid * 2 + half;
    if (i >= NTOK) return;

    float acc = -1e30f;
    if (n < NTAGS) {
        acc = out_b[n];
        const float4* hr = (const float4*)(h1 + (size_t)i * 200);
        const float4* wr = (const float4*)(out_w + (size_t)n * 200);
        #pragma unroll
        for (int e = 0; e < 50; ++e) {
            float4 h4 = hr[e], w4 = wr[e];
            acc += h4.x * w4.x + h4.y * w4.y + h4.z * w4.z + h4.w * w4.w;
        }
    }
    float m = acc;
    for (int off = 16; off > 0; off >>= 1) m = fmaxf(m, __shfl_xor(m, off, 32));
    float ex = (n < NTAGS) ? __expf(acc - m) : 0.f;
    float s = ex;
    for (int off = 16; off > 0; off >>= 1) s += __shfl_xor(s, off, 32);
    if (n < NTAGS) logits[(size_t)i * NTAGS + n] = acc - m - __logf(s);
}

// ---------------------------------------------------------------------------
// CRF loss: one wave per batch element.
// ---------------------------------------------------------------------------
__global__ __launch_bounds__(64) void crf_kernel(
    const float* __restrict__ logits,
    const int* __restrict__ words,
    const int* __restrict__ target,
    const float* __restrict__ trans,
    const float* __restrict__ start_s,
    const float* __restrict__ end_s,
    float* __restrict__ out)
{
    const int b = blockIdx.x;
    const int j = threadIdx.x;

    float tcol[NTAGS];
    #pragma unroll
    for (int i = 0; i < NTAGS; ++i) tcol[i] = (j < NTAGS) ? trans[i * NTAGS + j] : 0.f;

    float alpha = (j < NTAGS) ? (logits[(size_t)(0 * BB + b) * NTAGS + j] + start_s[j]) : -1e30f;

    for (int t = 1; t < TT; ++t) {
        bool mt = (words[b * TT + t] != 0);
        if (mt) {
            float v[NTAGS];
            float mx = -1e30f;
            #pragma unroll
            for (int i2 = 0; i2 < NTAGS; ++i2) {
                float ai = __shfl(alpha, i2, 64);
                v[i2] = ai + tcol[i2];
                mx = fmaxf(mx, v[i2]);
            }
            float s = 0.f;
            #pragma unroll
            for (int i2 = 0; i2 < NTAGS; ++i2) s += __expf(v[i2] - mx);
            float na = mx + __logf(s) + logits[(size_t)(t * BB + b) * NTAGS + j];
            alpha = (j < NTAGS) ? na : -1e30f;
        }
    }

    float val = (j < NTAGS) ? (alpha + end_s[j]) : -1e30f;
    float mx = val;
    for (int off = 32; off > 0; off >>= 1) mx = fmaxf(mx, __shfl_xor(mx, off, 64));
    float s = (j < NTAGS) ? __expf(val - mx) : 0.f;
    for (int off = 32; off > 0; off >>= 1) s += __shfl_xor(s, off, 64);
    float norm = mx + __logf(s);

    float gold = 0.f, slen = 0.f;
    for (int t = j; t < TT; t += 64) {
        int tg = target[b * TT + t];
        bool m = (words[b * TT + t] != 0);
        if (m) {
            gold += logits[(size_t)(t * BB + b) * NTAGS + tg];
            slen += 1.f;
            if (t >= 1) gold += trans[target[b * TT + t - 1] * NTAGS + tg];
        }
    }
    for (int off = 32; off > 0; off >>= 1) {
        gold += __shfl_xor(gold, off, 64);
        slen += __shfl_xor(slen, off, 64);
    }
    if (j == 0) {
        int len = (int)slen;
        int last = (len > 0) ? (len - 1) : 0;
        int last_tag = target[b * TT + last];
        gold += start_s[target[b * TT + 0]] + end_s[last_tag];
        out[b] = norm - gold;
    }
}

// ---------------------------------------------------------------------------
extern "C" void kernel_launch(void* const* d_in, const int* in_sizes, int n_in,
                              void* d_out, int out_size, void* d_ws, size_t ws_size,
                              hipStream_t stream) {
    const int*   words   = (const int*)  d_in[0];
    const int*   target  = (const int*)  d_in[1];
    const float* embed   = (const float*)d_in[2];
    const float* in_fc_w = (const float*)d_in[3];
    const float* in_fc_b = (const float*)d_in[4];
    const float* Wih0    = (const float*)d_in[5];
    const float* Whh0    = (const float*)d_in[6];
    const float* bih0    = (const float*)d_in[7];
    const float* bhh0    = (const float*)d_in[8];
    const float* Wih1    = (const float*)d_in[9];
    const float* Whh1    = (const float*)d_in[10];
    const float* bih1    = (const float*)d_in[11];
    const float* bhh1    = (const float*)d_in[12];
    const float* out_w   = (const float*)d_in[13];
    const float* out_b   = (const float*)d_in[14];
    const float* trans   = (const float*)d_in[15];
    const float* start_s = (const float*)d_in[16];
    const float* end_s   = (const float*)d_in[17];
    float* out = (float*)d_out;

    float* ws = (float*)d_ws;
    // layout (floats): x [0,2097152)  pre [2097152,8650752)  h0 [8650752,10289152)
    //                  h1 = x region  logits [1638400,1810432)
    float* x      = ws;
    float* pre    = ws + 2097152;
    float* h0     = ws + 8650752;
    float* h1     = ws;
    float* logits = ws + 1638400;

    // 1) x = gather(embed, words) @ in_fc_w^T + in_fc_b     (8192 x 256)
    gemm_mfma<<<dim3(64, 4), 256, 0, stream>>>(
        embed, EMBED, in_fc_w, EMBED, in_fc_b, nullptr,
        x, DMODEL, DMODEL, EMBED, words, 0);

    // 2) pre0 = x @ Wih0^T (gate-permuted) + (bih0 + bhh0)  (8192 x 800)
    gemm_mfma<<<dim3(64, 13), 256, 0, stream>>>(
        x, DMODEL, Wih0, DMODEL, bih0, bhh0,
        pre, 800, 800, DMODEL, nullptr, 1);

    // 3) layer0 recurrence -> h0 (8192 x 200)
    lstm_mfma<<<64, 448, 0, stream>>>(pre, Whh0, h0);

    // 4) pre1 = h0 @ Wih1^T (gate-permuted) + (bih1 + bhh1) (8192 x 800)
    gemm_mfma<<<dim3(64, 13), 256, 0, stream>>>(
        h0, 200, Wih1, 200, bih1, bhh1,
        pre, 800, 800, 200, nullptr, 1);

    // 5) layer1 recurrence -> h1 (8192 x 200)
    lstm_mfma<<<64, 448, 0, stream>>>(pre, Whh1, h1);

    // 6) logits + log_softmax (8192 x 21)
    logits_lsm<<<NTOK / 8, 256, 0, stream>>>(h1, out_w, out_b, logits);

    // 7) CRF loss -> out (32)
    crf_kernel<<<BB, 64, 0, stream>>>(logits, words, target, trans, start_s, end_s, out);
}